// Round 6
// baseline (316.016 us; speedup 1.0000x reference)
//
#include <hip/hip_runtime.h>
#include <cfloat>
#include <cmath>
#include <cstdint>

#define N_NODES 128
#define F_IN    256
#define HDIM    512
#define NEDGE   524288
#define NREP    32   // z0r replicas for head GEMV atomics

typedef _Float16 half8 __attribute__((ext_vector_type(8)));
typedef _Float16 half4 __attribute__((ext_vector_type(4)));
typedef float f32x4 __attribute__((ext_vector_type(4)));

// ---------------------------------------------------------------------------
// uv body: U[d,h] = A[d]@(Wtop-Wbot)(+b), V[d,h] = A[d]@Wbot.
// KK = input feature count (A row stride; W has 2*KK rows).
// Block: 128 d x 16 h, K-slice of KK/S. atomicAdd into zeroed U/V.
// smem layout: As[128][33] f32 | Wd[32][20] | Wb[32][20]  = 22016 B
// ---------------------------------------------------------------------------
template <int KK, int S>
__device__ __forceinline__ void uv_body(
    const float* __restrict__ A, const float* __restrict__ W,
    const float* __restrict__ bias, float* __restrict__ U,
    float* __restrict__ V, const int h0, const int ks0, const bool addb,
    char* smem) {
  constexpr int KS = KK / S;
  constexpr int BK = 32;
  float(*As)[BK + 1] = (float(*)[BK + 1])smem;
  float(*Wd)[20] = (float(*)[20])(smem + 128 * (BK + 1) * 4);
  float(*Wb)[20] = (float(*)[20])(smem + 128 * (BK + 1) * 4 + BK * 20 * 4);
  const int t = threadIdx.x;
  const int tx = t & 3;
  const int ty = t >> 2;

  float accU[2][4], accV[2][4];
#pragma unroll
  for (int i = 0; i < 2; ++i)
#pragma unroll
    for (int j = 0; j < 4; ++j) { accU[i][j] = 0.f; accV[i][j] = 0.f; }

  for (int ch = 0; ch < KS / BK; ++ch) {
    const int k0 = ks0 + ch * BK;
    __syncthreads();
    // A chunk: 128 d x 32 k (1024 float4, 4/thread)
#pragma unroll
    for (int i = 0; i < 4; ++i) {
      const int slot = t + i * 256;
      const int dd = slot >> 3, kw = (slot & 7) * 4;
      const float4 a4 =
          *reinterpret_cast<const float4*>(&A[dd * KK + k0 + kw]);
      As[dd][kw + 0] = a4.x;
      As[dd][kw + 1] = a4.y;
      As[dd][kw + 2] = a4.z;
      As[dd][kw + 3] = a4.w;
    }
    // W chunk: 32 k x 16 h top+bot (threads 0..127)
    if (t < 128) {
      const int k = t >> 2, hq = (t & 3) * 4;
      const float4 wt = *reinterpret_cast<const float4*>(
          &W[(size_t)(k0 + k) * HDIM + h0 + hq]);
      const float4 wb = *reinterpret_cast<const float4*>(
          &W[(size_t)(KK + k0 + k) * HDIM + h0 + hq]);
      *reinterpret_cast<float4*>(&Wb[k][hq]) = wb;
      float4 wd;
      wd.x = wt.x - wb.x; wd.y = wt.y - wb.y;
      wd.z = wt.z - wb.z; wd.w = wt.w - wb.w;
      *reinterpret_cast<float4*>(&Wd[k][hq]) = wd;
    }
    __syncthreads();
#pragma unroll
    for (int k = 0; k < BK; ++k) {
      float a[2];
#pragma unroll
      for (int i = 0; i < 2; ++i) a[i] = As[ty * 2 + i][k];
      const float4 wd4 = *reinterpret_cast<const float4*>(&Wd[k][tx * 4]);
      const float4 wb4 = *reinterpret_cast<const float4*>(&Wb[k][tx * 4]);
      const float wdv[4] = {wd4.x, wd4.y, wd4.z, wd4.w};
      const float wbv[4] = {wb4.x, wb4.y, wb4.z, wb4.w};
#pragma unroll
      for (int i = 0; i < 2; ++i)
#pragma unroll
        for (int j = 0; j < 4; ++j) {
          accU[i][j] = fmaf(a[i], wdv[j], accU[i][j]);
          accV[i][j] = fmaf(a[i], wbv[j], accV[i][j]);
        }
    }
  }
  const int cbase = h0 + tx * 4;
  float bb[4] = {0.f, 0.f, 0.f, 0.f};
  if (addb) {
#pragma unroll
    for (int j = 0; j < 4; ++j) bb[j] = bias[cbase + j];
  }
#pragma unroll
  for (int i = 0; i < 2; ++i) {
    const int row = ty * 2 + i;
#pragma unroll
    for (int j = 0; j < 4; ++j) {
      atomicAdd(&U[row * HDIM + cbase + j], accU[i][j] + bb[j]);
      atomicAdd(&V[row * HDIM + cbase + j], accV[i][j]);
    }
  }
}

// ---------------------------------------------------------------------------
// FUSED front: blocks [0,128) run uv layer-1 (x @ c1_W1, KK=256, 4 K-slices
// of 64); blocks [128,384) build adjacency bitmask; blocks [384,512)
// transpose W2 -> f16 [n][k]. 512 blocks = whole machine; block-uniform
// branches.
// ---------------------------------------------------------------------------
__global__ __launch_bounds__(256) void prep_uv1_kernel(
    const int* __restrict__ ei, unsigned int* __restrict__ mask,
    const float* __restrict__ W2a, const float* __restrict__ W2b,
    _Float16* __restrict__ Ta, _Float16* __restrict__ Tb,
    const float* __restrict__ x, const float* __restrict__ W1,
    const float* __restrict__ b1, float* __restrict__ U1,
    float* __restrict__ V1) {
  __shared__ __align__(16) char smem[22016];
  const int bx = blockIdx.x;
  const int t = threadIdx.x;
  if (bx < 128) {
    const int hx = bx & 31, ky = bx >> 5;
    // KK=256 (x row stride), S=4 -> KS=64 per slice, ks0 = ky*64.
    uv_body<F_IN, 4>(x, W1, b1, U1, V1, hx * 16, ky * (F_IN / 4),
                     ky == 0, smem);
  } else if (bx < 384) {
    unsigned int* lm = (unsigned int*)smem;
    for (int i = t; i < N_NODES * 4; i += 256) lm[i] = 0u;
    __syncthreads();
    const int base = (bx - 128) * 2048;
#pragma unroll
    for (int r = 0; r < 8; ++r) {
      const int e = base + r * 256 + t;
      const int s = ei[e];          // src  (x_j)
      const int d = ei[NEDGE + e];  // dst  (segment target)
      atomicOr(&lm[d * 4 + (s >> 5)], 1u << (s & 31));
    }
    __syncthreads();
    for (int i = t; i < N_NODES * 4; i += 256) {
      const unsigned int v = lm[i];
      if (v) atomicOr(&mask[i], v);
    }
  } else {
    const int b = bx - 384;
    const int layer = b >> 6;
    const int rem = b & 63;
    const int kb = (rem & 7) * 64;
    const int nb = (rem >> 3) * 64;
    const float* W = layer ? W2b : W2a;
    _Float16* T = layer ? Tb : Ta;
    _Float16(*tile)[72] = (_Float16(*)[72])smem;
#pragma unroll
    for (int i = 0; i < 4; ++i) {
      const int slot = t + i * 256;
      const int kk = slot >> 4;
      const int nq = (slot & 15) * 4;
      const float4 w4 = *reinterpret_cast<const float4*>(
          &W[(size_t)(kb + kk) * HDIM + nb + nq]);
      tile[nq + 0][kk] = (_Float16)w4.x;
      tile[nq + 1][kk] = (_Float16)w4.y;
      tile[nq + 2][kk] = (_Float16)w4.z;
      tile[nq + 3][kk] = (_Float16)w4.w;
    }
    __syncthreads();
#pragma unroll
    for (int i = 0; i < 2; ++i) {
      const int slot = t + i * 256;
      const int n = slot >> 3;
      const int ko = (slot & 7) * 8;
      *reinterpret_cast<half8*>(&T[(size_t)(nb + n) * HDIM + kb + ko]) =
          *reinterpret_cast<const half8*>(&tile[n][ko]);
    }
  }
}

// ---------------------------------------------------------------------------
// uv layer-2 standalone: grid (32 h-tiles, 8 K-slices) = 256 blocks.
// ---------------------------------------------------------------------------
template <int KK, int S>
__global__ __launch_bounds__(256) void uv_gemm_kernel(
    const float* __restrict__ A, const float* __restrict__ W,
    const float* __restrict__ bias, float* __restrict__ U,
    float* __restrict__ V) {
  __shared__ __align__(16) char smem[22016];
  uv_body<KK, S>(A, W, bias, U, V, blockIdx.x * 16, blockIdx.y * (KK / S),
                 blockIdx.y == 0, smem);
}

// ---------------------------------------------------------------------------
// K2/K4: MFMA fp16 pair GEMM + fused masked max + bias + relu (lean).
// ---------------------------------------------------------------------------
#define PBK 64
__global__ __launch_bounds__(256) void pair_mfma_kernel(
    const float* __restrict__ U, const float* __restrict__ V,
    const _Float16* __restrict__ W2t, const float* __restrict__ b2,
    const unsigned int* __restrict__ mask, float* __restrict__ out) {
  __shared__ __align__(16) _Float16 As[128][PBK + 8];
  __shared__ _Float16 Bs[128][PBK + 8];
  __shared__ float Ur[HDIM];
  __shared__ float red[4][128];
  const int t = threadIdx.x;
  const int d = blockIdx.y;
  const int c0 = blockIdx.x * 128;
  const int lane = t & 63;
  const int wid = t >> 6;
  const int l15 = lane & 15;
  const int quad = lane >> 4;

  for (int i = t; i < HDIM; i += 256) Ur[i] = U[d * HDIM + i];
  const unsigned int mwv[4] = {mask[d * 4 + 0], mask[d * 4 + 1],
                               mask[d * 4 + 2], mask[d * 4 + 3]};

  f32x4 acc[8][2];
#pragma unroll
  for (int mt = 0; mt < 8; ++mt)
#pragma unroll
    for (int nt = 0; nt < 2; ++nt) acc[mt][nt] = (f32x4)(0.f);

  for (int ch = 0; ch < HDIM / PBK; ++ch) {
    const int k0 = ch * PBK;
    __syncthreads();
#pragma unroll
    for (int i = 0; i < 8; ++i) {
      const int slot = t + i * 256;
      const int s = slot >> 4;
      const int kq = (slot & 15) * 4;
      const float4 v4 =
          *reinterpret_cast<const float4*>(&V[s * HDIM + k0 + kq]);
      const float4 u4 = *reinterpret_cast<const float4*>(&Ur[k0 + kq]);
      half4 h;
      h.x = (_Float16)fmaxf(u4.x + v4.x, 0.f);
      h.y = (_Float16)fmaxf(u4.y + v4.y, 0.f);
      h.z = (_Float16)fmaxf(u4.z + v4.z, 0.f);
      h.w = (_Float16)fmaxf(u4.w + v4.w, 0.f);
      *reinterpret_cast<half4*>(&As[s][kq]) = h;
    }
#pragma unroll
    for (int i = 0; i < 4; ++i) {
      const int slot = t + i * 256;
      const int n = slot >> 3;
      const int ko = (slot & 7) * 8;
      *reinterpret_cast<half8*>(&Bs[n][ko]) = *reinterpret_cast<const half8*>(
          &W2t[(size_t)(c0 + n) * HDIM + k0 + ko]);
    }
    __syncthreads();
#pragma unroll
    for (int ks = 0; ks < PBK / 32; ++ks) {
      half8 bf[2];
#pragma unroll
      for (int nt = 0; nt < 2; ++nt)
        bf[nt] = *reinterpret_cast<const half8*>(
            &Bs[wid * 32 + nt * 16 + l15][ks * 32 + quad * 8]);
#pragma unroll
      for (int mt = 0; mt < 8; ++mt) {
        const half8 af = *reinterpret_cast<const half8*>(
            &As[mt * 16 + l15][ks * 32 + quad * 8]);
#pragma unroll
        for (int nt = 0; nt < 2; ++nt)
          acc[mt][nt] = __builtin_amdgcn_mfma_f32_16x16x32_f16(
              af, bf[nt], acc[mt][nt], 0, 0, 0);
      }
    }
  }
  __syncthreads();
#pragma unroll
  for (int nt = 0; nt < 2; ++nt) {
    float pm = -FLT_MAX;
#pragma unroll
    for (int mt = 0; mt < 8; ++mt) {
      const int sbase = mt * 16 + quad * 4;
      const unsigned int w = mwv[sbase >> 5] >> (sbase & 31);
#pragma unroll
      for (int r = 0; r < 4; ++r)
        if ((w >> r) & 1u) pm = fmaxf(pm, acc[mt][nt][r]);
    }
    red[quad][wid * 32 + nt * 16 + l15] = pm;
  }
  __syncthreads();
  if (t < 128) {
    const float m = fmaxf(fmaxf(red[0][t], red[1][t]),
                          fmaxf(red[2][t], red[3][t]));
    out[d * HDIM + c0 + t] = fmaxf(m + b2[c0 + t], 0.f);
  }
}

// ---------------------------------------------------------------------------
// K5 v7: head GEMV as a copy-bench-style grid-stride stream.
// Slot = f32x4 unit of lin_W (8M slots). i = bid*256 + tid + k*524288,
// k=0..15. Row = i>>7 (wave-uniform v-load), cols = (i&127)*4 — constant
// per thread since the stride is a multiple of the row width. One W-load +
// one v-load + 4 FMAs per iteration: a steady stream the compiler can
// software-pipeline (no batch/drain stalls). 8 blocks/CU (2 KB LDS, low
// VGPR) = full occupancy. Pair-reduce (t, t+128) in LDS, then 4 atomicAdds
// per low thread into 32 XCD-local z0r replicas (contention 64/addr).
// ---------------------------------------------------------------------------
__global__ __launch_bounds__(256) void head_gemv7_kernel(
    const float* __restrict__ v, const float* __restrict__ W,
    float* __restrict__ z0r) {
  __shared__ float red2[512];
  const int t = threadIdx.x;
  const int b = blockIdx.x;
  const int base = b * 256 + t;  // slot index in f32x4 units
  const f32x4* Wp = reinterpret_cast<const f32x4*>(W);
  f32x4 acc = (f32x4)(0.f);
#pragma unroll
  for (int k = 0; k < 16; ++k) {
    const int i = base + k * 524288;
    const float xv = v[i >> 7];
    const f32x4 w4 = Wp[i];
    acc.x = fmaf(xv, w4.x, acc.x);
    acc.y = fmaf(xv, w4.y, acc.y);
    acc.z = fmaf(xv, w4.z, acc.z);
    acc.w = fmaf(xv, w4.w, acc.w);
  }
  if (t >= 128) *reinterpret_cast<f32x4*>(&red2[(t - 128) * 4]) = acc;
  __syncthreads();
  if (t < 128) {
    const f32x4 o = *reinterpret_cast<const f32x4*>(&red2[t * 4]);
    float* zr = z0r + (size_t)(b & (NREP - 1)) * 512 + t * 4;
    atomicAdd(&zr[0], acc.x + o.x);
    atomicAdd(&zr[1], acc.y + o.y);
    atomicAdd(&zr[2], acc.z + o.z);
    atomicAdd(&zr[3], acc.w + o.w);
  }
}

// ---------------------------------------------------------------------------
// K6 (fused tail): z0 = sum_NREP z0r; z1 = relu(relu(z0+b)@lin1W + b1);
// z2 = relu(z1@outW + b2); out = softmax(z2). One block, 512 threads.
// ---------------------------------------------------------------------------
__global__ __launch_bounds__(512) void head_tail_kernel(
    const float* __restrict__ z0r, const float* __restrict__ lin_b,
    const float* __restrict__ lin1W, const float* __restrict__ lin1b,
    const float* __restrict__ outW, const float* __restrict__ outb,
    float* __restrict__ out) {
  __shared__ float zr[512];
  __shared__ float r1[2][256];
  __shared__ float z1s[256];
  __shared__ float r2[4][128];
  __shared__ float z2s[128];
  __shared__ float rr[128];
  const int t = threadIdx.x;
  {
    float s = 0.f;
#pragma unroll
    for (int r = 0; r < NREP; ++r) s += z0r[r * 512 + t];
    zr[t] = fmaxf(s + lin_b[t], 0.f);
  }
  __syncthreads();
  // z1: col = t&255, k-half = t>>8 (256 k each), 16-deep batches
  {
    const int c = t & 255;
    const int kh = t >> 8;
    float acc = 0.f;
#pragma unroll
    for (int b2 = 0; b2 < 16; ++b2) {
      const int k0 = kh * 256 + b2 * 16;
      float wv[16];
#pragma unroll
      for (int i = 0; i < 16; ++i) wv[i] = lin1W[(size_t)(k0 + i) * 256 + c];
#pragma unroll
      for (int i = 0; i < 16; ++i) acc = fmaf(zr[k0 + i], wv[i], acc);
    }
    r1[kh][c] = acc;
  }
  __syncthreads();
  if (t < 256) z1s[t] = fmaxf(r1[0][t] + r1[1][t] + lin1b[t], 0.f);
  __syncthreads();
  // z2: col = t&127, k-quarter = t>>7 (64 k each)
  {
    const int c = t & 127;
    const int kq = t >> 7;
    float acc = 0.f;
#pragma unroll
    for (int b2 = 0; b2 < 4; ++b2) {
      const int k0 = kq * 64 + b2 * 16;
      float wv[16];
#pragma unroll
      for (int i = 0; i < 16; ++i) wv[i] = outW[(size_t)(k0 + i) * 128 + c];
#pragma unroll
      for (int i = 0; i < 16; ++i) acc = fmaf(z1s[k0 + i], wv[i], acc);
    }
    r2[kq][c] = acc;
  }
  __syncthreads();
  if (t < 128) {
    const float z =
        fmaxf(r2[0][t] + r2[1][t] + r2[2][t] + r2[3][t] + outb[t], 0.f);
    z2s[t] = z;
    rr[t] = z;
  }
  __syncthreads();
  for (int off = 64; off > 0; off >>= 1) {
    if (t < off) rr[t] = fmaxf(rr[t], rr[t + off]);
    __syncthreads();
  }
  const float mx = rr[0];
  __syncthreads();
  if (t < 128) {
    const float e = expf(z2s[t] - mx);
    z2s[t] = e;
    rr[t] = e;
  }
  __syncthreads();
  for (int off = 64; off > 0; off >>= 1) {
    if (t < off) rr[t] += rr[t + off];
    __syncthreads();
  }
  if (t < 128) out[t] = z2s[t] / rr[0];
}

// ---------------------------------------------------------------------------
extern "C" void kernel_launch(void* const* d_in, const int* in_sizes, int n_in,
                              void* d_out, int out_size, void* d_ws,
                              size_t ws_size, hipStream_t stream) {
  const float* x      = (const float*)d_in[0];
  const int*   ei     = (const int*)d_in[1];
  const float* c1_W1  = (const float*)d_in[2];
  const float* c1_b1  = (const float*)d_in[3];
  const float* c1_W2  = (const float*)d_in[4];
  const float* c1_b2  = (const float*)d_in[5];
  const float* c2_W1  = (const float*)d_in[6];
  const float* c2_b1  = (const float*)d_in[7];
  const float* c2_W2  = (const float*)d_in[8];
  const float* c2_b2  = (const float*)d_in[9];
  const float* lin_W  = (const float*)d_in[10];
  const float* lin_b  = (const float*)d_in[11];
  const float* lin1_W = (const float*)d_in[12];
  const float* lin1_b = (const float*)d_in[13];
  const float* out_W  = (const float*)d_in[14];
  const float* out_b  = (const float*)d_in[15];
  float* out = (float*)d_out;

  char* wsb = (char*)d_ws;
  // Zeroed region: mask | z0r[NREP][512] | U1 V1 U2 V2   (single memset)
  unsigned int* mask = (unsigned int*)wsb;          // 2048 B
  float* z0r = (float*)(wsb + 2048);                // NREP*512 floats
  float* U1 = z0r + NREP * 512;                     // 128x512 f32 each
  float* V1 = U1 + 65536;
  float* U2 = V1 + 65536;
  float* V2 = U2 + 65536;
  const size_t zero_bytes = 2048 + (size_t)NREP * 512 * 4 + 4 * 65536 * 4;
  // Non-zeroed scratch:
  float* h1 = V2 + 65536;                           // 128x512 f32
  float* h2 = h1 + 65536;
  _Float16* W2t1 = (_Float16*)(h2 + 65536);         // 512x512 f16 each
  _Float16* W2t2 = W2t1 + 262144;

  hipMemsetAsync(wsb, 0, zero_bytes, stream);
  prep_uv1_kernel<<<512, 256, 0, stream>>>(ei, mask, c1_W2, c2_W2, W2t1, W2t2,
                                           x, c1_W1, c1_b1, U1, V1);
  pair_mfma_kernel<<<dim3(4, 128), 256, 0, stream>>>(U1, V1, W2t1, c1_b2,
                                                     mask, h1);
  uv_gemm_kernel<512, 8><<<dim3(32, 8), 256, 0, stream>>>(h1, c2_W1, c2_b1,
                                                          U2, V2);
  pair_mfma_kernel<<<dim3(4, 128), 256, 0, stream>>>(U2, V2, W2t2, c2_b2,
                                                     mask, h2);
  head_gemv7_kernel<<<2048, 256, 0, stream>>>(h2, lin_W, z0r);
  head_tail_kernel<<<1, 512, 0, stream>>>(z0r, lin_b, lin1_W, lin1_b, out_W,
                                          out_b, out);
}

// Round 7
// 304.623 us; speedup vs baseline: 1.0374x; 1.0374x over previous
//
#include <hip/hip_runtime.h>
#include <cfloat>
#include <cmath>
#include <cstdint>

#define N_NODES 128
#define F_IN    256
#define HDIM    512
#define NEDGE   524288
#define NREP    32   // z0r replicas for head GEMV atomics

typedef _Float16 half8 __attribute__((ext_vector_type(8)));
typedef _Float16 half4 __attribute__((ext_vector_type(4)));
typedef float f32x4 __attribute__((ext_vector_type(4)));

// ---------------------------------------------------------------------------
// uv body: U[d,h] = A[d]@(Wtop-Wbot)(+b), V[d,h] = A[d]@Wbot.
// KK = input feature count (A row stride; W has 2*KK rows).
// Block: 128 d x 16 h, K-slice of KK/S. atomicAdd into zeroed U/V.
// smem layout: As[128][33] f32 | Wd[32][20] | Wb[32][20]  = 22016 B
// ---------------------------------------------------------------------------
template <int KK, int S>
__device__ __forceinline__ void uv_body(
    const float* __restrict__ A, const float* __restrict__ W,
    const float* __restrict__ bias, float* __restrict__ U,
    float* __restrict__ V, const int h0, const int ks0, const bool addb,
    char* smem) {
  constexpr int KS = KK / S;
  constexpr int BK = 32;
  float(*As)[BK + 1] = (float(*)[BK + 1])smem;
  float(*Wd)[20] = (float(*)[20])(smem + 128 * (BK + 1) * 4);
  float(*Wb)[20] = (float(*)[20])(smem + 128 * (BK + 1) * 4 + BK * 20 * 4);
  const int t = threadIdx.x;
  const int tx = t & 3;
  const int ty = t >> 2;

  float accU[2][4], accV[2][4];
#pragma unroll
  for (int i = 0; i < 2; ++i)
#pragma unroll
    for (int j = 0; j < 4; ++j) { accU[i][j] = 0.f; accV[i][j] = 0.f; }

  for (int ch = 0; ch < KS / BK; ++ch) {
    const int k0 = ks0 + ch * BK;
    __syncthreads();
    // A chunk: 128 d x 32 k (1024 float4, 4/thread)
#pragma unroll
    for (int i = 0; i < 4; ++i) {
      const int slot = t + i * 256;
      const int dd = slot >> 3, kw = (slot & 7) * 4;
      const float4 a4 =
          *reinterpret_cast<const float4*>(&A[dd * KK + k0 + kw]);
      As[dd][kw + 0] = a4.x;
      As[dd][kw + 1] = a4.y;
      As[dd][kw + 2] = a4.z;
      As[dd][kw + 3] = a4.w;
    }
    // W chunk: 32 k x 16 h top+bot (threads 0..127)
    if (t < 128) {
      const int k = t >> 2, hq = (t & 3) * 4;
      const float4 wt = *reinterpret_cast<const float4*>(
          &W[(size_t)(k0 + k) * HDIM + h0 + hq]);
      const float4 wb = *reinterpret_cast<const float4*>(
          &W[(size_t)(KK + k0 + k) * HDIM + h0 + hq]);
      *reinterpret_cast<float4*>(&Wb[k][hq]) = wb;
      float4 wd;
      wd.x = wt.x - wb.x; wd.y = wt.y - wb.y;
      wd.z = wt.z - wb.z; wd.w = wt.w - wb.w;
      *reinterpret_cast<float4*>(&Wd[k][hq]) = wd;
    }
    __syncthreads();
#pragma unroll
    for (int k = 0; k < BK; ++k) {
      float a[2];
#pragma unroll
      for (int i = 0; i < 2; ++i) a[i] = As[ty * 2 + i][k];
      const float4 wd4 = *reinterpret_cast<const float4*>(&Wd[k][tx * 4]);
      const float4 wb4 = *reinterpret_cast<const float4*>(&Wb[k][tx * 4]);
      const float wdv[4] = {wd4.x, wd4.y, wd4.z, wd4.w};
      const float wbv[4] = {wb4.x, wb4.y, wb4.z, wb4.w};
#pragma unroll
      for (int i = 0; i < 2; ++i)
#pragma unroll
        for (int j = 0; j < 4; ++j) {
          accU[i][j] = fmaf(a[i], wdv[j], accU[i][j]);
          accV[i][j] = fmaf(a[i], wbv[j], accV[i][j]);
        }
    }
  }
  const int cbase = h0 + tx * 4;
  float bb[4] = {0.f, 0.f, 0.f, 0.f};
  if (addb) {
#pragma unroll
    for (int j = 0; j < 4; ++j) bb[j] = bias[cbase + j];
  }
#pragma unroll
  for (int i = 0; i < 2; ++i) {
    const int row = ty * 2 + i;
#pragma unroll
    for (int j = 0; j < 4; ++j) {
      atomicAdd(&U[row * HDIM + cbase + j], accU[i][j] + bb[j]);
      atomicAdd(&V[row * HDIM + cbase + j], accV[i][j]);
    }
  }
}

// ---------------------------------------------------------------------------
// FUSED front: blocks [0,128) run uv layer-1 (x @ c1_W1, KK=256, 4 K-slices
// of 64); blocks [128,384) build adjacency bitmask; blocks [384,512)
// transpose W2 -> f16 [n][k]. 512 blocks = whole machine; block-uniform
// branches.
// ---------------------------------------------------------------------------
__global__ __launch_bounds__(256) void prep_uv1_kernel(
    const int* __restrict__ ei, unsigned int* __restrict__ mask,
    const float* __restrict__ W2a, const float* __restrict__ W2b,
    _Float16* __restrict__ Ta, _Float16* __restrict__ Tb,
    const float* __restrict__ x, const float* __restrict__ W1,
    const float* __restrict__ b1, float* __restrict__ U1,
    float* __restrict__ V1) {
  __shared__ __align__(16) char smem[22016];
  const int bx = blockIdx.x;
  const int t = threadIdx.x;
  if (bx < 128) {
    const int hx = bx & 31, ky = bx >> 5;
    // KK=256 (x row stride), S=4 -> KS=64 per slice, ks0 = ky*64.
    uv_body<F_IN, 4>(x, W1, b1, U1, V1, hx * 16, ky * (F_IN / 4),
                     ky == 0, smem);
  } else if (bx < 384) {
    unsigned int* lm = (unsigned int*)smem;
    for (int i = t; i < N_NODES * 4; i += 256) lm[i] = 0u;
    __syncthreads();
    const int base = (bx - 128) * 2048;
#pragma unroll
    for (int r = 0; r < 8; ++r) {
      const int e = base + r * 256 + t;
      const int s = ei[e];          // src  (x_j)
      const int d = ei[NEDGE + e];  // dst  (segment target)
      atomicOr(&lm[d * 4 + (s >> 5)], 1u << (s & 31));
    }
    __syncthreads();
    for (int i = t; i < N_NODES * 4; i += 256) {
      const unsigned int v = lm[i];
      if (v) atomicOr(&mask[i], v);
    }
  } else {
    const int b = bx - 384;
    const int layer = b >> 6;
    const int rem = b & 63;
    const int kb = (rem & 7) * 64;
    const int nb = (rem >> 3) * 64;
    const float* W = layer ? W2b : W2a;
    _Float16* T = layer ? Tb : Ta;
    _Float16(*tile)[72] = (_Float16(*)[72])smem;
#pragma unroll
    for (int i = 0; i < 4; ++i) {
      const int slot = t + i * 256;
      const int kk = slot >> 4;
      const int nq = (slot & 15) * 4;
      const float4 w4 = *reinterpret_cast<const float4*>(
          &W[(size_t)(kb + kk) * HDIM + nb + nq]);
      tile[nq + 0][kk] = (_Float16)w4.x;
      tile[nq + 1][kk] = (_Float16)w4.y;
      tile[nq + 2][kk] = (_Float16)w4.z;
      tile[nq + 3][kk] = (_Float16)w4.w;
    }
    __syncthreads();
#pragma unroll
    for (int i = 0; i < 2; ++i) {
      const int slot = t + i * 256;
      const int n = slot >> 3;
      const int ko = (slot & 7) * 8;
      *reinterpret_cast<half8*>(&T[(size_t)(nb + n) * HDIM + kb + ko]) =
          *reinterpret_cast<const half8*>(&tile[n][ko]);
    }
  }
}

// ---------------------------------------------------------------------------
// uv layer-2 standalone: grid (32 h-tiles, 8 K-slices) = 256 blocks.
// ---------------------------------------------------------------------------
template <int KK, int S>
__global__ __launch_bounds__(256) void uv_gemm_kernel(
    const float* __restrict__ A, const float* __restrict__ W,
    const float* __restrict__ bias, float* __restrict__ U,
    float* __restrict__ V) {
  __shared__ __align__(16) char smem[22016];
  uv_body<KK, S>(A, W, bias, U, V, blockIdx.x * 16, blockIdx.y * (KK / S),
                 blockIdx.y == 0, smem);
}

// ---------------------------------------------------------------------------
// K2/K4: MFMA fp16 pair GEMM + fused masked max + bias + relu (lean).
// ---------------------------------------------------------------------------
#define PBK 64
__global__ __launch_bounds__(256) void pair_mfma_kernel(
    const float* __restrict__ U, const float* __restrict__ V,
    const _Float16* __restrict__ W2t, const float* __restrict__ b2,
    const unsigned int* __restrict__ mask, float* __restrict__ out) {
  __shared__ __align__(16) _Float16 As[128][PBK + 8];
  __shared__ _Float16 Bs[128][PBK + 8];
  __shared__ float Ur[HDIM];
  __shared__ float red[4][128];
  const int t = threadIdx.x;
  const int d = blockIdx.y;
  const int c0 = blockIdx.x * 128;
  const int lane = t & 63;
  const int wid = t >> 6;
  const int l15 = lane & 15;
  const int quad = lane >> 4;

  for (int i = t; i < HDIM; i += 256) Ur[i] = U[d * HDIM + i];
  const unsigned int mwv[4] = {mask[d * 4 + 0], mask[d * 4 + 1],
                               mask[d * 4 + 2], mask[d * 4 + 3]};

  f32x4 acc[8][2];
#pragma unroll
  for (int mt = 0; mt < 8; ++mt)
#pragma unroll
    for (int nt = 0; nt < 2; ++nt) acc[mt][nt] = (f32x4)(0.f);

  for (int ch = 0; ch < HDIM / PBK; ++ch) {
    const int k0 = ch * PBK;
    __syncthreads();
#pragma unroll
    for (int i = 0; i < 8; ++i) {
      const int slot = t + i * 256;
      const int s = slot >> 4;
      const int kq = (slot & 15) * 4;
      const float4 v4 =
          *reinterpret_cast<const float4*>(&V[s * HDIM + k0 + kq]);
      const float4 u4 = *reinterpret_cast<const float4*>(&Ur[k0 + kq]);
      half4 h;
      h.x = (_Float16)fmaxf(u4.x + v4.x, 0.f);
      h.y = (_Float16)fmaxf(u4.y + v4.y, 0.f);
      h.z = (_Float16)fmaxf(u4.z + v4.z, 0.f);
      h.w = (_Float16)fmaxf(u4.w + v4.w, 0.f);
      *reinterpret_cast<half4*>(&As[s][kq]) = h;
    }
#pragma unroll
    for (int i = 0; i < 4; ++i) {
      const int slot = t + i * 256;
      const int n = slot >> 3;
      const int ko = (slot & 7) * 8;
      *reinterpret_cast<half8*>(&Bs[n][ko]) = *reinterpret_cast<const half8*>(
          &W2t[(size_t)(c0 + n) * HDIM + k0 + ko]);
    }
    __syncthreads();
#pragma unroll
    for (int ks = 0; ks < PBK / 32; ++ks) {
      half8 bf[2];
#pragma unroll
      for (int nt = 0; nt < 2; ++nt)
        bf[nt] = *reinterpret_cast<const half8*>(
            &Bs[wid * 32 + nt * 16 + l15][ks * 32 + quad * 8]);
#pragma unroll
      for (int mt = 0; mt < 8; ++mt) {
        const half8 af = *reinterpret_cast<const half8*>(
            &As[mt * 16 + l15][ks * 32 + quad * 8]);
#pragma unroll
        for (int nt = 0; nt < 2; ++nt)
          acc[mt][nt] = __builtin_amdgcn_mfma_f32_16x16x32_f16(
              af, bf[nt], acc[mt][nt], 0, 0, 0);
      }
    }
  }
  __syncthreads();
#pragma unroll
  for (int nt = 0; nt < 2; ++nt) {
    float pm = -FLT_MAX;
#pragma unroll
    for (int mt = 0; mt < 8; ++mt) {
      const int sbase = mt * 16 + quad * 4;
      const unsigned int w = mwv[sbase >> 5] >> (sbase & 31);
#pragma unroll
      for (int r = 0; r < 4; ++r)
        if ((w >> r) & 1u) pm = fmaxf(pm, acc[mt][nt][r]);
    }
    red[quad][wid * 32 + nt * 16 + l15] = pm;
  }
  __syncthreads();
  if (t < 128) {
    const float m = fmaxf(fmaxf(red[0][t], red[1][t]),
                          fmaxf(red[2][t], red[3][t]));
    out[d * HDIM + c0 + t] = fmaxf(m + b2[c0 + t], 0.f);
  }
}

// ---------------------------------------------------------------------------
// K5 v8: head GEMV — v6 loop structure, 2x occupancy probe.
// 2048 blocks x 32 rows (8 blocks/CU nominal, 32 waves/CU). Wave w owns
// rows [w*8, +8); single batch of 8 rows = 16 float4 loads in flight per
// thread (same depth as v6, half the per-thread work, 2x resident waves).
// Contiguous per-instruction addressing: accA cols [4l,4l+4), accB cols
// [256+4l,+4). 32 replicas -> contention 64/address.
// ---------------------------------------------------------------------------
__global__ __launch_bounds__(256) void head_gemv8_kernel(
    const float* __restrict__ v, const float* __restrict__ W,
    float* __restrict__ z0r) {
  __shared__ float vs[32];
  __shared__ float red[4][512];
  const int t = threadIdx.x;
  const int b = blockIdx.x;
  const int r0 = b * 32;
  if (t < 32) vs[t] = v[r0 + t];
  __syncthreads();
  const int w = t >> 6;
  const int l = t & 63;
  const float* WpA = W + (size_t)(r0 + w * 8) * 512 + l * 4;
  float4 accA = make_float4(0.f, 0.f, 0.f, 0.f);
  float4 accB = make_float4(0.f, 0.f, 0.f, 0.f);
  {
    float4 wa[8], wb[8];
#pragma unroll
    for (int i = 0; i < 8; ++i) {
      const float* p = WpA + (size_t)i * 512;
      wa[i] = *reinterpret_cast<const float4*>(p);
      wb[i] = *reinterpret_cast<const float4*>(p + 256);
    }
#pragma unroll
    for (int i = 0; i < 8; ++i) {
      const float xv = vs[w * 8 + i];
      accA.x = fmaf(xv, wa[i].x, accA.x);
      accA.y = fmaf(xv, wa[i].y, accA.y);
      accA.z = fmaf(xv, wa[i].z, accA.z);
      accA.w = fmaf(xv, wa[i].w, accA.w);
      accB.x = fmaf(xv, wb[i].x, accB.x);
      accB.y = fmaf(xv, wb[i].y, accB.y);
      accB.z = fmaf(xv, wb[i].z, accB.z);
      accB.w = fmaf(xv, wb[i].w, accB.w);
    }
  }
  // accA -> cols l*4..+4 ; accB -> cols 256+l*4..+4
  *reinterpret_cast<float4*>(&red[w][l * 4]) = accA;
  *reinterpret_cast<float4*>(&red[w][256 + l * 4]) = accB;
  __syncthreads();
  float* zr = z0r + (size_t)(b & (NREP - 1)) * 512;
  const float s0 = red[0][t] + red[1][t] + red[2][t] + red[3][t];
  const int c2 = t + 256;
  const float s1 = red[0][c2] + red[1][c2] + red[2][c2] + red[3][c2];
  atomicAdd(&zr[t], s0);
  atomicAdd(&zr[c2], s1);
}

// ---------------------------------------------------------------------------
// K6 (fused tail): z0 = sum_NREP z0r; z1 = relu(relu(z0+b)@lin1W + b1);
// z2 = relu(z1@outW + b2); out = softmax(z2). One block, 512 threads.
// ---------------------------------------------------------------------------
__global__ __launch_bounds__(512) void head_tail_kernel(
    const float* __restrict__ z0r, const float* __restrict__ lin_b,
    const float* __restrict__ lin1W, const float* __restrict__ lin1b,
    const float* __restrict__ outW, const float* __restrict__ outb,
    float* __restrict__ out) {
  __shared__ float zr[512];
  __shared__ float r1[2][256];
  __shared__ float z1s[256];
  __shared__ float r2[4][128];
  __shared__ float z2s[128];
  __shared__ float rr[128];
  const int t = threadIdx.x;
  {
    float s = 0.f;
#pragma unroll
    for (int r = 0; r < NREP; ++r) s += z0r[r * 512 + t];
    zr[t] = fmaxf(s + lin_b[t], 0.f);
  }
  __syncthreads();
  // z1: col = t&255, k-half = t>>8 (256 k each), 16-deep batches
  {
    const int c = t & 255;
    const int kh = t >> 8;
    float acc = 0.f;
#pragma unroll
    for (int b2 = 0; b2 < 16; ++b2) {
      const int k0 = kh * 256 + b2 * 16;
      float wv[16];
#pragma unroll
      for (int i = 0; i < 16; ++i) wv[i] = lin1W[(size_t)(k0 + i) * 256 + c];
#pragma unroll
      for (int i = 0; i < 16; ++i) acc = fmaf(zr[k0 + i], wv[i], acc);
    }
    r1[kh][c] = acc;
  }
  __syncthreads();
  if (t < 256) z1s[t] = fmaxf(r1[0][t] + r1[1][t] + lin1b[t], 0.f);
  __syncthreads();
  // z2: col = t&127, k-quarter = t>>7 (64 k each)
  {
    const int c = t & 127;
    const int kq = t >> 7;
    float acc = 0.f;
#pragma unroll
    for (int b2 = 0; b2 < 4; ++b2) {
      const int k0 = kq * 64 + b2 * 16;
      float wv[16];
#pragma unroll
      for (int i = 0; i < 16; ++i) wv[i] = outW[(size_t)(k0 + i) * 128 + c];
#pragma unroll
      for (int i = 0; i < 16; ++i) acc = fmaf(z1s[k0 + i], wv[i], acc);
    }
    r2[kq][c] = acc;
  }
  __syncthreads();
  if (t < 128) {
    const float z =
        fmaxf(r2[0][t] + r2[1][t] + r2[2][t] + r2[3][t] + outb[t], 0.f);
    z2s[t] = z;
    rr[t] = z;
  }
  __syncthreads();
  for (int off = 64; off > 0; off >>= 1) {
    if (t < off) rr[t] = fmaxf(rr[t], rr[t + off]);
    __syncthreads();
  }
  const float mx = rr[0];
  __syncthreads();
  if (t < 128) {
    const float e = expf(z2s[t] - mx);
    z2s[t] = e;
    rr[t] = e;
  }
  __syncthreads();
  for (int off = 64; off > 0; off >>= 1) {
    if (t < off) rr[t] += rr[t + off];
    __syncthreads();
  }
  if (t < 128) out[t] = z2s[t] / rr[0];
}

// ---------------------------------------------------------------------------
extern "C" void kernel_launch(void* const* d_in, const int* in_sizes, int n_in,
                              void* d_out, int out_size, void* d_ws,
                              size_t ws_size, hipStream_t stream) {
  const float* x      = (const float*)d_in[0];
  const int*   ei     = (const int*)d_in[1];
  const float* c1_W1  = (const float*)d_in[2];
  const float* c1_b1  = (const float*)d_in[3];
  const float* c1_W2  = (const float*)d_in[4];
  const float* c1_b2  = (const float*)d_in[5];
  const float* c2_W1  = (const float*)d_in[6];
  const float* c2_b1  = (const float*)d_in[7];
  const float* c2_W2  = (const float*)d_in[8];
  const float* c2_b2  = (const float*)d_in[9];
  const float* lin_W  = (const float*)d_in[10];
  const float* lin_b  = (const float*)d_in[11];
  const float* lin1_W = (const float*)d_in[12];
  const float* lin1_b = (const float*)d_in[13];
  const float* out_W  = (const float*)d_in[14];
  const float* out_b  = (const float*)d_in[15];
  float* out = (float*)d_out;

  char* wsb = (char*)d_ws;
  // Zeroed region: mask | z0r[NREP][512] | U1 V1 U2 V2   (single memset)
  unsigned int* mask = (unsigned int*)wsb;          // 2048 B
  float* z0r = (float*)(wsb + 2048);                // NREP*512 floats
  float* U1 = z0r + NREP * 512;                     // 128x512 f32 each
  float* V1 = U1 + 65536;
  float* U2 = V1 + 65536;
  float* V2 = U2 + 65536;
  const size_t zero_bytes = 2048 + (size_t)NREP * 512 * 4 + 4 * 65536 * 4;
  // Non-zeroed scratch:
  float* h1 = V2 + 65536;                           // 128x512 f32
  float* h2 = h1 + 65536;
  _Float16* W2t1 = (_Float16*)(h2 + 65536);         // 512x512 f16 each
  _Float16* W2t2 = W2t1 + 262144;

  hipMemsetAsync(wsb, 0, zero_bytes, stream);
  prep_uv1_kernel<<<512, 256, 0, stream>>>(ei, mask, c1_W2, c2_W2, W2t1, W2t2,
                                           x, c1_W1, c1_b1, U1, V1);
  pair_mfma_kernel<<<dim3(4, 128), 256, 0, stream>>>(U1, V1, W2t1, c1_b2,
                                                     mask, h1);
  uv_gemm_kernel<512, 8><<<dim3(32, 8), 256, 0, stream>>>(h1, c2_W1, c2_b1,
                                                          U2, V2);
  pair_mfma_kernel<<<dim3(4, 128), 256, 0, stream>>>(U2, V2, W2t2, c2_b2,
                                                     mask, h2);
  head_gemv8_kernel<<<2048, 256, 0, stream>>>(h2, lin_W, z0r);
  head_tail_kernel<<<1, 512, 0, stream>>>(z0r, lin_b, lin1_W, lin1_b, out_W,
                                          out_b, out);
}